// Round 1
// baseline (407.127 us; speedup 1.0000x reference)
//
#include <hip/hip_runtime.h>
#include <hip/hip_bf16.h>
#include <stdint.h>

// B=2, N=128, D=512, LAYERS=3.
// Key structural fact: rel1 -> rel2 -> rel3 -> S is a PER-ROW map over the
// [32768,512] tensor (row r=(b,i,j): rel_{k+1}[r,:] = tanh(rel_k[r,:]@Wgc +
// p_i + q_j)).  So the whole chain is fused into one kernel: each block holds
// a 64-row panel in LDS (bf16, XOR-swizzled) and runs 3 in-place K=512 GEMM
// stages with v_mfma_f32_32x32x16_bf16, W streamed from L2.  No R1/R2
// intermediates ever touch HBM; only S (needed twice by softmax) is written.
// Softmax over axis i is computed WITHOUT the max pass: |s| <= ~23, far from
// f32 exp overflow; softmax is shift-invariant so result matches reference.

#define DEV static __device__ __forceinline__

typedef float  f32x4   __attribute__((ext_vector_type(4)));
typedef float  f32x16  __attribute__((ext_vector_type(16)));
typedef __bf16 bf16x8  __attribute__((ext_vector_type(8)));
typedef __bf16 bf16x4  __attribute__((ext_vector_type(4)));

DEV float tanh_fast(float x) {
  float e = __expf(2.0f * x);
  return 1.0f - 2.0f * __frcp_rn(e + 1.0f);
}

DEV void gl_lds16(const void* g, void* l) {
  __builtin_amdgcn_global_load_lds(
      (const __attribute__((address_space(1))) unsigned int*)g,
      (__attribute__((address_space(3))) unsigned int*)l, 16, 0, 0);
}

// ------------- prep: weight transpose->bf16 hi/lo, x0 split, dvec ---------------
struct WC { const float* W; __bf16* Wh; __bf16* Wl; };
struct Prep {
  WC w[7];
  const float* x0; __bf16* x0h; __bf16* x0l;
  const float* b_rel; const float* Wgrc; const float* b_gr; float* dvec;
};

__global__ __launch_bounds__(256) void prep_kernel(Prep pp) {
  const int y = blockIdx.y;
  if (y < 7) {
    const WC wc = pp.w[y];
    __shared__ float tile[32][33];
    int t = threadIdx.x;
    int tx = t & 31, ty = t >> 5;                     // 32 x 8
    int bx = blockIdx.x & 15, by = blockIdx.x >> 4;   // 16 x 16 tiles of 32x32
    int k0 = by * 32, n0 = bx * 32;
#pragma unroll
    for (int r = 0; r < 4; ++r) {
      int k = ty + r * 8;
      tile[k][tx] = wc.W[(size_t)(k0 + k) * 512 + n0 + tx];
    }
    __syncthreads();
#pragma unroll
    for (int r = 0; r < 4; ++r) {
      int n = ty + r * 8;
      float v = tile[tx][n];
      __bf16 h = (__bf16)v;
      wc.Wh[(size_t)(n0 + n) * 512 + k0 + tx] = h;
      wc.Wl[(size_t)(n0 + n) * 512 + k0 + tx] = (__bf16)(v - (float)h);
    }
  } else if (y == 7) {
    int i = blockIdx.x * 256 + threadIdx.x;
    if (i < 32768) {
      float4 v = ((const float4*)pp.x0)[i];
      float vv[4] = {v.x, v.y, v.z, v.w};
      bf16x4 h, l;
#pragma unroll
      for (int e = 0; e < 4; ++e) {
        __bf16 he = (__bf16)vv[e];
        h[e] = he;
        l[e] = (__bf16)(vv[e] - (float)he);
      }
      ((bf16x4*)pp.x0h)[i] = h;
      ((bf16x4*)pp.x0l)[i] = l;
    }
  } else {
    if (blockIdx.x < 2) {
      int n = blockIdx.x * 256 + threadIdx.x;
      float acc = pp.b_gr[n];
#pragma unroll 8
      for (int k = 0; k < 512; ++k) acc += pp.b_rel[k] * pp.Wgrc[(size_t)k * 512 + n];
      pp.dvec[n] = acc;
    }
  }
}

// ------------- small MFMA GEMM batch: out = act(X@W + bias + add) ---------------
// M=256, N=512, K=512. 64x64 tiles, split-precision compensated bf16.
struct MOp {
  const __bf16* Xh; const __bf16* Xl;   // [256,512]
  const __bf16* Wh; const __bf16* Wl;   // [512(n),512(k)] transposed
  const float* bias;                    // [512] or null
  const float* add;                     // [256,512] or null
  float* outf;                          // [256,512] or null
  __bf16* outh; __bf16* outl;           // [256,512] or null
  int act;                              // 1 = tanh
};
struct MBatch { MOp op[5]; };

__global__ __launch_bounds__(256, 2) void mfma_small_kernel(MBatch batch) {
  const MOp o = batch.op[blockIdx.y];
  const int m0 = ((int)blockIdx.x >> 3) * 64;
  const int n0 = ((int)blockIdx.x & 7) * 64;
  __shared__ __bf16 Ah[64 * 64], Al[64 * 64], Bh[64 * 64], Bl[64 * 64];
  const int t = threadIdx.x, lane = t & 63, wave = t >> 6;
  const int waveM = wave >> 1, waveN = wave & 1;
  const bool comp = (o.Xl != nullptr);

  f32x4 vzero = {0.f, 0.f, 0.f, 0.f};
  f32x4 acc[2][2];
#pragma unroll
  for (int a = 0; a < 2; ++a)
#pragma unroll
    for (int c = 0; c < 2; ++c) acc[a][c] = vzero;

  const int lr = lane >> 3, lc = (lane & 7) * 8;

  for (int k0 = 0; k0 < 512; k0 += 64) {
    __syncthreads();
#pragma unroll
    for (int r = 0; r < 2; ++r) {
      const int rb = r * 32 + wave * 8;
      gl_lds16(o.Xh + (size_t)(m0 + rb + lr) * 512 + k0 + lc, &Ah[rb * 64]);
      gl_lds16(o.Wh + (size_t)(n0 + rb + lr) * 512 + k0 + lc, &Bh[rb * 64]);
      if (comp) {
        gl_lds16(o.Xl + (size_t)(m0 + rb + lr) * 512 + k0 + lc, &Al[rb * 64]);
        gl_lds16(o.Wl + (size_t)(n0 + rb + lr) * 512 + k0 + lc, &Bl[rb * 64]);
      }
    }
    __syncthreads();
#pragma unroll
    for (int kk = 0; kk < 2; ++kk) {
      const int koff = kk * 32 + (lane >> 4) * 8;
      const int ml = lane & 15;
      bf16x8 ah[2], bh[2], al[2], bl[2];
#pragma unroll
      for (int tm = 0; tm < 2; ++tm)
        ah[tm] = *(const bf16x8*)&Ah[(waveM * 32 + tm * 16 + ml) * 64 + koff];
#pragma unroll
      for (int tn = 0; tn < 2; ++tn)
        bh[tn] = *(const bf16x8*)&Bh[(waveN * 32 + tn * 16 + ml) * 64 + koff];
      if (comp) {
#pragma unroll
        for (int tm = 0; tm < 2; ++tm)
          al[tm] = *(const bf16x8*)&Al[(waveM * 32 + tm * 16 + ml) * 64 + koff];
#pragma unroll
        for (int tn = 0; tn < 2; ++tn)
          bl[tn] = *(const bf16x8*)&Bl[(waveN * 32 + tn * 16 + ml) * 64 + koff];
      }
#pragma unroll
      for (int tm = 0; tm < 2; ++tm)
#pragma unroll
        for (int tn = 0; tn < 2; ++tn) {
          acc[tm][tn] = __builtin_amdgcn_mfma_f32_16x16x32_bf16(ah[tm], bh[tn], acc[tm][tn], 0, 0, 0);
          if (comp) {
            acc[tm][tn] = __builtin_amdgcn_mfma_f32_16x16x32_bf16(ah[tm], bl[tn], acc[tm][tn], 0, 0, 0);
            acc[tm][tn] = __builtin_amdgcn_mfma_f32_16x16x32_bf16(al[tm], bh[tn], acc[tm][tn], 0, 0, 0);
          }
        }
    }
  }

  const int quad = lane >> 4, cl = lane & 15;
#pragma unroll
  for (int tm = 0; tm < 2; ++tm) {
#pragma unroll
    for (int r = 0; r < 4; ++r) {
      const int row = m0 + waveM * 32 + tm * 16 + quad * 4 + r;
#pragma unroll
      for (int tn = 0; tn < 2; ++tn) {
        const int col = n0 + waveN * 32 + tn * 16 + cl;
        float v = acc[tm][tn][r];
        if (o.bias) v += o.bias[col];
        if (o.add) v += o.add[(size_t)row * 512 + col];
        if (o.act) v = tanh_fast(v);
        if (o.outf) o.outf[(size_t)row * 512 + col] = v;
        if (o.outh) {
          __bf16 h = (__bf16)v;
          o.outh[(size_t)row * 512 + col] = h;
          o.outl[(size_t)row * 512 + col] = (__bf16)(v - (float)h);
        }
      }
    }
  }
}

// ------------- fused chain kernel --------------------------------------------
// Each block: 64-row panel (one (b,i), 64 consecutive j), P[64][512] bf16 in
// LDS.  P is XOR-swizzled: byte ^= (row&15)<<4 -> the stride-1024B A-fragment
// ds_read_b128 pattern becomes bank-uniform (rows 0..15 hit 16 distinct 16B
// slots; rows r / r+16 alias 2-way, which is free).
// Stage: acc[64x512] = P @ W^T  (A from LDS, B streamed global/L2),
// then P = tanh(acc + p_i + q_j) in place (stages 1,2) or S = acc + b_esa
// written to global (stage 3).
DEV int p_byte(int row, int col /*bf16 index*/) {
  return row * 1024 + ((col * 2) ^ ((row & 15) << 4));
}

template <bool FINAL>
DEV void chain_stage(__bf16* P, const __bf16* __restrict__ Wt,
                     const float* __restrict__ pv,  // [512] (p_i slice or b_esa)
                     const float* __restrict__ qv,  // [64,512] rows j0.. (null if FINAL)
                     float* __restrict__ Sout,      // S + r0*512 (FINAL only)
                     int lane, int wave) {
  const int ml = lane & 31, kl = lane >> 5;
  f32x16 acc[2][4];
#pragma unroll
  for (int tm = 0; tm < 2; ++tm)
#pragma unroll
    for (int tn = 0; tn < 4; ++tn) acc[tm][tn] = (f32x16)0.f;

  const __bf16* wbase = Wt + (size_t)(wave * 128 + ml) * 512 + kl * 8;
#pragma unroll 4
  for (int ks = 0; ks < 32; ++ks) {
    bf16x8 af[2], bfr[4];
#pragma unroll
    for (int tn = 0; tn < 4; ++tn)
      bfr[tn] = *(const bf16x8*)&wbase[(size_t)(tn * 32) * 512 + ks * 16];
#pragma unroll
    for (int tm = 0; tm < 2; ++tm)
      af[tm] = *(const bf16x8*)((const char*)P + p_byte(tm * 32 + ml, ks * 16 + kl * 8));
#pragma unroll
    for (int tm = 0; tm < 2; ++tm)
#pragma unroll
      for (int tn = 0; tn < 4; ++tn)
        acc[tm][tn] = __builtin_amdgcn_mfma_f32_32x32x16_bf16(af[tm], bfr[tn], acc[tm][tn], 0, 0, 0);
  }

  __syncthreads();  // all waves done READING P before it is overwritten

  const int cl = lane & 31, lg = lane >> 5;
#pragma unroll
  for (int tm = 0; tm < 2; ++tm)
#pragma unroll
    for (int tn = 0; tn < 4; ++tn) {
      const int col = wave * 128 + tn * 32 + cl;
      const float pval = pv[col];
#pragma unroll
      for (int reg = 0; reg < 16; ++reg) {
        const int row = tm * 32 + (reg & 3) + 8 * (reg >> 2) + 4 * lg;
        float v = acc[tm][tn][reg] + pval;
        if constexpr (FINAL) {
          Sout[(size_t)row * 512 + col] = v;
        } else {
          v += qv[(size_t)row * 512 + col];
          *(__bf16*)((char*)P + p_byte(row, col)) = (__bf16)tanh_fast(v);
        }
      }
    }
  if constexpr (!FINAL) __syncthreads();
}

__global__ __launch_bounds__(256, 2) void chain_kernel(
    const float* __restrict__ A, const float* __restrict__ C,
    const __bf16* __restrict__ Wgc, const __bf16* __restrict__ Wes,
    const float* __restrict__ p1, const float* __restrict__ q1,
    const float* __restrict__ p2, const float* __restrict__ q2,
    const float* __restrict__ b_esa, float* __restrict__ S) {
  __shared__ __bf16 P[64 * 512];  // 64 KB, swizzled via p_byte
  const int t = threadIdx.x, lane = t & 63, wave = t >> 6;
  const int blk = blockIdx.x;           // 512 blocks
  const size_t r0 = (size_t)blk * 64;   // global row = (b*128+i)*128 + j
  const int bi = blk >> 1;              // b*128 + i
  const int b = bi >> 7;
  const int j0 = (blk & 1) * 64;

  // ---- rel1 fill: P[r][d] = tanh(A[bi][d] + C[b*128+j0+r][d]) ----
  {
    const float* arow = A + (size_t)bi * 512;
#pragma unroll
    for (int c = 0; c < 16; ++c) {
      int chunk = c * 256 + t;          // 4096 chunks = 64 rows x 64 chunks
      int row = chunk >> 6;
      int col = (chunk & 63) * 8;
      const float* ap = arow + col;
      const float* cp = C + ((size_t)(b * 128 + j0 + row)) * 512 + col;
      float av[8], cv[8];
      *(float4*)&av[0] = *(const float4*)ap;
      *(float4*)&av[4] = *(const float4*)(ap + 4);
      *(float4*)&cv[0] = *(const float4*)cp;
      *(float4*)&cv[4] = *(const float4*)(cp + 4);
      bf16x8 o;
#pragma unroll
      for (int e = 0; e < 8; ++e) o[e] = (__bf16)tanh_fast(av[e] + cv[e]);
      *(bf16x8*)((char*)P + p_byte(row, col)) = o;
    }
  }
  __syncthreads();

  // rel2 = tanh(P@Wgc + p1_i + q1_j)
  chain_stage<false>(P, Wgc, p1 + (size_t)bi * 512,
                     q1 + ((size_t)(b * 128 + j0)) * 512, nullptr, lane, wave);
  // rel3 = tanh(P@Wgc + p2_i + q2_j)
  chain_stage<false>(P, Wgc, p2 + (size_t)bi * 512,
                     q2 + ((size_t)(b * 128 + j0)) * 512, nullptr, lane, wave);
  // S = P@Wes + b_esa
  chain_stage<true>(P, Wes, b_esa, nullptr, S + r0 * 512, lane, wave);
}

// ------------- softmax over axis i (no max pass: |s| bounded), then sum over j --
__global__ __launch_bounds__(256) void softmax_l_kernel(
    const float* __restrict__ S, float* __restrict__ Lb) {
  int idx = blockIdx.x * 256 + threadIdx.x;   // = (b*128 + j)*512 + d
  int d = idx & 511;
  int j = (idx >> 9) & 127;
  int b = idx >> 16;
  const float* p = S + ((size_t)b * 16384 + j) * 512 + d;  // i = 0
  float l = 0.f;
#pragma unroll 8
  for (int ii = 0; ii < 128; ++ii) l += __expf(p[(size_t)ii * 65536]);
  Lb[idx] = __frcp_rn(l);
}

__global__ __launch_bounds__(256) void softmax_out_kernel(
    const float* __restrict__ S, const float* __restrict__ Lb,
    float* __restrict__ outp) {
  int idx = blockIdx.x * 256 + threadIdx.x;   // = (b*128 + i)*512 + d
  int d = idx & 511;
  int i = (idx >> 9) & 127;
  int b = idx >> 16;
  const float* sp = S + ((size_t)(b * 128 + i)) * 65536 + d;  // j = 0
  const float* lp = Lb + (size_t)b * 65536 + d;
  float acc = 0.f;
#pragma unroll 8
  for (int jj = 0; jj < 128; ++jj) {
    float s = sp[(size_t)jj * 512];
    acc += __expf(s) * lp[(size_t)jj * 512] * s;
  }
  outp[idx] = acc;
}

// --------------------------------------------------------------------------------
extern "C" void kernel_launch(void* const* d_in, const int* in_sizes, int n_in,
                              void* d_out, int out_size, void* d_ws, size_t ws_size,
                              hipStream_t stream) {
  const float* x0    = (const float*)d_in[0];
  const float* W_rel = (const float*)d_in[1];
  const float* b_rel = (const float*)d_in[2];
  const float* W_go  = (const float*)d_in[3];
  const float* b_go  = (const float*)d_in[4];
  const float* W_gr  = (const float*)d_in[5];
  const float* b_gr  = (const float*)d_in[6];
  const float* W_esa = (const float*)d_in[7];
  const float* b_esa = (const float*)d_in[8];

  const float* Wrel_top = W_rel;
  const float* Wrel_bot = W_rel + 512 * 512;
  const float* Wgr_a = W_gr;
  const float* Wgr_b = W_gr + 512 * 512;
  const float* Wgr_c = W_gr + 2 * 512 * 512;

  char* ws = (char*)d_ws;
  size_t off = 0;
  auto alloc = [&](size_t bytes) -> void* {
    void* p = ws + off;
    off += (bytes + 255) & ~(size_t)255;
    return p;
  };
  const size_t NREL = 16777216ull;  // B*N*N*D
  float*  S  = (float*)alloc(NREL * 4);        // 64 MB
  float* p0t  = (float*)alloc(131072 * 4);
  float* q0t  = (float*)alloc(131072 * 4);
  float* Abuf = (float*)alloc(131072 * 4);
  float* Cbuf = (float*)alloc(131072 * 4);
  float* p1   = (float*)alloc(131072 * 4);
  float* q1   = (float*)alloc(131072 * 4);
  float* p2   = (float*)alloc(131072 * 4);
  float* q2   = (float*)alloc(131072 * 4);
  float* dvec = (float*)alloc(512 * 4);
  float* Lb   = (float*)alloc(131072 * 4);
  __bf16* x0h = (__bf16*)alloc(131072 * 2);
  __bf16* x0l = (__bf16*)alloc(131072 * 2);
  __bf16* x1h = (__bf16*)alloc(131072 * 2);
  __bf16* x1l = (__bf16*)alloc(131072 * 2);
  __bf16* x2h = (__bf16*)alloc(131072 * 2);
  __bf16* x2l = (__bf16*)alloc(131072 * 2);
  __bf16* u0h = (__bf16*)alloc(131072 * 2);
  __bf16* u0l = (__bf16*)alloc(131072 * 2);
  __bf16* v0h = (__bf16*)alloc(131072 * 2);
  __bf16* v0l = (__bf16*)alloc(131072 * 2);
  __bf16* Wgo_h = (__bf16*)alloc(262144 * 2);
  __bf16* Wgo_l = (__bf16*)alloc(262144 * 2);
  __bf16* Wrt_h = (__bf16*)alloc(262144 * 2);
  __bf16* Wrt_l = (__bf16*)alloc(262144 * 2);
  __bf16* Wrb_h = (__bf16*)alloc(262144 * 2);
  __bf16* Wrb_l = (__bf16*)alloc(262144 * 2);
  __bf16* Wga_h = (__bf16*)alloc(262144 * 2);
  __bf16* Wga_l = (__bf16*)alloc(262144 * 2);
  __bf16* Wgb_h = (__bf16*)alloc(262144 * 2);
  __bf16* Wgb_l = (__bf16*)alloc(262144 * 2);
  __bf16* Wgc_h = (__bf16*)alloc(262144 * 2);
  __bf16* Wgc_l = (__bf16*)alloc(262144 * 2);
  __bf16* Wes_h = (__bf16*)alloc(262144 * 2);
  __bf16* Wes_l = (__bf16*)alloc(262144 * 2);

  float* x3out  = (float*)d_out;             // output 0
  float* relout = (float*)d_out + 131072;    // output 1

  Prep pp;
  pp.w[0] = {W_go, Wgo_h, Wgo_l};
  pp.w[1] = {Wrel_top, Wrt_h, Wrt_l};
  pp.w[2] = {Wrel_bot, Wrb_h, Wrb_l};
  pp.w[3] = {Wgr_a, Wga_h, Wga_l};
  pp.w[4] = {Wgr_b, Wgb_h, Wgb_l};
  pp.w[5] = {Wgr_c, Wgc_h, Wgc_l};
  pp.w[6] = {W_esa, Wes_h, Wes_l};
  pp.x0 = x0; pp.x0h = x0h; pp.x0l = x0l;
  pp.b_rel = b_rel; pp.Wgrc = Wgr_c; pp.b_gr = b_gr; pp.dvec = dvec;
  prep_kernel<<<dim3(256, 9), 256, 0, stream>>>(pp);

  MBatch m1 = {};
  m1.op[0] = {x0h, x0l, Wgo_h, Wgo_l, b_go, nullptr, nullptr, x1h, x1l, 1};
  m1.op[1] = {x0h, x0l, Wrt_h, Wrt_l, nullptr, nullptr, nullptr, u0h, u0l, 0};
  m1.op[2] = {x0h, x0l, Wrb_h, Wrb_l, nullptr, nullptr, nullptr, v0h, v0l, 0};
  m1.op[3] = {x0h, x0l, Wga_h, Wga_l, nullptr, nullptr, p0t, nullptr, nullptr, 0};
  m1.op[4] = {x0h, x0l, Wgb_h, Wgb_l, nullptr, nullptr, q0t, nullptr, nullptr, 0};
  mfma_small_kernel<<<dim3(32, 5), 256, 0, stream>>>(m1);

  MBatch m2 = {};
  m2.op[0] = {x1h, x1l, Wgo_h, Wgo_l, b_go, nullptr, nullptr, x2h, x2l, 1};
  m2.op[1] = {u0h, u0l, Wgc_h, Wgc_l, dvec, p0t, Abuf, nullptr, nullptr, 0};
  m2.op[2] = {v0h, v0l, Wgc_h, Wgc_l, nullptr, q0t, Cbuf, nullptr, nullptr, 0};
  m2.op[3] = {x1h, x1l, Wga_h, Wga_l, b_gr, nullptr, p1, nullptr, nullptr, 0};
  m2.op[4] = {x1h, x1l, Wgb_h, Wgb_l, nullptr, nullptr, q1, nullptr, nullptr, 0};
  mfma_small_kernel<<<dim3(32, 5), 256, 0, stream>>>(m2);

  MBatch m3 = {};
  m3.op[0] = {x2h, x2l, Wgo_h, Wgo_l, b_go, nullptr, x3out, nullptr, nullptr, 1};
  m3.op[1] = {x2h, x2l, Wga_h, Wga_l, b_gr, nullptr, p2, nullptr, nullptr, 0};
  m3.op[2] = {x2h, x2l, Wgb_h, Wgb_l, nullptr, nullptr, q2, nullptr, nullptr, 0};
  mfma_small_kernel<<<dim3(32, 3), 256, 0, stream>>>(m3);

  // fused: rel1 (in LDS) -> rel2 -> rel3 -> S, one dispatch
  chain_kernel<<<512, 256, 0, stream>>>(Abuf, Cbuf, Wgc_h, Wes_h,
                                        p1, q1, p2, q2, b_esa, S);

  softmax_l_kernel<<<512, 256, 0, stream>>>(S, Lb);
  softmax_out_kernel<<<512, 256, 0, stream>>>(S, Lb, relout);
}

// Round 2
// 392.046 us; speedup vs baseline: 1.0385x; 1.0385x over previous
//
#include <hip/hip_runtime.h>
#include <hip/hip_bf16.h>
#include <stdint.h>

// B=2, N=128, D=512, LAYERS=3.
// rel1 -> rel2 -> rel3 -> S is a PER-ROW map over [32768,512]: row r=(b,i,j):
// rel_{k+1}[r,:] = tanh(rel_k[r,:]@Wgc + p_i + q_j).  Fused chain kernel:
// each block holds a 64-row panel P in LDS (bf16, XOR-swizzled) and runs 3
// K=512 GEMM stages with v_mfma_f32_32x32x16_bf16.  B-operand (W) is staged
// through LDS via global_load_lds, double-buffered [512n x 32k] tiles --
// round-1's per-lane strided global B-loads (64 lines/inst, 4x L2 re-fetch)
// were the regression; this restores coalesced 1KB staging.
// Softmax over axis i without the max pass: |s| <= ~23 << f32 exp overflow;
// softmax is shift-invariant so result matches the stable reference.

#define DEV static __device__ __forceinline__

typedef float  f32x4   __attribute__((ext_vector_type(4)));
typedef float  f32x16  __attribute__((ext_vector_type(16)));
typedef __bf16 bf16x8  __attribute__((ext_vector_type(8)));
typedef __bf16 bf16x4  __attribute__((ext_vector_type(4)));

DEV float tanh_fast(float x) {
  float e = __expf(2.0f * x);
  return 1.0f - 2.0f * __frcp_rn(e + 1.0f);
}

DEV void gl_lds16(const void* g, void* l) {
  __builtin_amdgcn_global_load_lds(
      (const __attribute__((address_space(1))) unsigned int*)g,
      (__attribute__((address_space(3))) unsigned int*)l, 16, 0, 0);
}

// ------------- prep: weight transpose->bf16 hi/lo, x0 split, dvec ---------------
struct WC { const float* W; __bf16* Wh; __bf16* Wl; };
struct Prep {
  WC w[7];
  const float* x0; __bf16* x0h; __bf16* x0l;
  const float* b_rel; const float* Wgrc; const float* b_gr; float* dvec;
};

__global__ __launch_bounds__(256) void prep_kernel(Prep pp) {
  const int y = blockIdx.y;
  if (y < 7) {
    const WC wc = pp.w[y];
    __shared__ float tile[32][33];
    int t = threadIdx.x;
    int tx = t & 31, ty = t >> 5;                     // 32 x 8
    int bx = blockIdx.x & 15, by = blockIdx.x >> 4;   // 16 x 16 tiles of 32x32
    int k0 = by * 32, n0 = bx * 32;
#pragma unroll
    for (int r = 0; r < 4; ++r) {
      int k = ty + r * 8;
      tile[k][tx] = wc.W[(size_t)(k0 + k) * 512 + n0 + tx];
    }
    __syncthreads();
#pragma unroll
    for (int r = 0; r < 4; ++r) {
      int n = ty + r * 8;
      float v = tile[tx][n];
      __bf16 h = (__bf16)v;
      wc.Wh[(size_t)(n0 + n) * 512 + k0 + tx] = h;
      wc.Wl[(size_t)(n0 + n) * 512 + k0 + tx] = (__bf16)(v - (float)h);
    }
  } else if (y == 7) {
    int i = blockIdx.x * 256 + threadIdx.x;
    if (i < 32768) {
      float4 v = ((const float4*)pp.x0)[i];
      float vv[4] = {v.x, v.y, v.z, v.w};
      bf16x4 h, l;
#pragma unroll
      for (int e = 0; e < 4; ++e) {
        __bf16 he = (__bf16)vv[e];
        h[e] = he;
        l[e] = (__bf16)(vv[e] - (float)he);
      }
      ((bf16x4*)pp.x0h)[i] = h;
      ((bf16x4*)pp.x0l)[i] = l;
    }
  } else {
    if (blockIdx.x < 2) {
      int n = blockIdx.x * 256 + threadIdx.x;
      float acc = pp.b_gr[n];
#pragma unroll 8
      for (int k = 0; k < 512; ++k) acc += pp.b_rel[k] * pp.Wgrc[(size_t)k * 512 + n];
      pp.dvec[n] = acc;
    }
  }
}

// ------------- small MFMA GEMM batch: out = act(X@W + bias + add) ---------------
struct MOp {
  const __bf16* Xh; const __bf16* Xl;   // [256,512]
  const __bf16* Wh; const __bf16* Wl;   // [512(n),512(k)] transposed
  const float* bias;                    // [512] or null
  const float* add;                     // [256,512] or null
  float* outf;                          // [256,512] or null
  __bf16* outh; __bf16* outl;           // [256,512] or null
  int act;                              // 1 = tanh
};
struct MBatch { MOp op[5]; };

__global__ __launch_bounds__(256, 2) void mfma_small_kernel(MBatch batch) {
  const MOp o = batch.op[blockIdx.y];
  const int m0 = ((int)blockIdx.x >> 3) * 64;
  const int n0 = ((int)blockIdx.x & 7) * 64;
  __shared__ __bf16 Ah[64 * 64], Al[64 * 64], Bh[64 * 64], Bl[64 * 64];
  const int t = threadIdx.x, lane = t & 63, wave = t >> 6;
  const int waveM = wave >> 1, waveN = wave & 1;
  const bool comp = (o.Xl != nullptr);

  f32x4 vzero = {0.f, 0.f, 0.f, 0.f};
  f32x4 acc[2][2];
#pragma unroll
  for (int a = 0; a < 2; ++a)
#pragma unroll
    for (int c = 0; c < 2; ++c) acc[a][c] = vzero;

  const int lr = lane >> 3, lc = (lane & 7) * 8;

  for (int k0 = 0; k0 < 512; k0 += 64) {
    __syncthreads();
#pragma unroll
    for (int r = 0; r < 2; ++r) {
      const int rb = r * 32 + wave * 8;
      gl_lds16(o.Xh + (size_t)(m0 + rb + lr) * 512 + k0 + lc, &Ah[rb * 64]);
      gl_lds16(o.Wh + (size_t)(n0 + rb + lr) * 512 + k0 + lc, &Bh[rb * 64]);
      if (comp) {
        gl_lds16(o.Xl + (size_t)(m0 + rb + lr) * 512 + k0 + lc, &Al[rb * 64]);
        gl_lds16(o.Wl + (size_t)(n0 + rb + lr) * 512 + k0 + lc, &Bl[rb * 64]);
      }
    }
    __syncthreads();
#pragma unroll
    for (int kk = 0; kk < 2; ++kk) {
      const int koff = kk * 32 + (lane >> 4) * 8;
      const int ml = lane & 15;
      bf16x8 ah[2], bh[2], al[2], bl[2];
#pragma unroll
      for (int tm = 0; tm < 2; ++tm)
        ah[tm] = *(const bf16x8*)&Ah[(waveM * 32 + tm * 16 + ml) * 64 + koff];
#pragma unroll
      for (int tn = 0; tn < 2; ++tn)
        bh[tn] = *(const bf16x8*)&Bh[(waveN * 32 + tn * 16 + ml) * 64 + koff];
      if (comp) {
#pragma unroll
        for (int tm = 0; tm < 2; ++tm)
          al[tm] = *(const bf16x8*)&Al[(waveM * 32 + tm * 16 + ml) * 64 + koff];
#pragma unroll
        for (int tn = 0; tn < 2; ++tn)
          bl[tn] = *(const bf16x8*)&Bl[(waveN * 32 + tn * 16 + ml) * 64 + koff];
      }
#pragma unroll
      for (int tm = 0; tm < 2; ++tm)
#pragma unroll
        for (int tn = 0; tn < 2; ++tn) {
          acc[tm][tn] = __builtin_amdgcn_mfma_f32_16x16x32_bf16(ah[tm], bh[tn], acc[tm][tn], 0, 0, 0);
          if (comp) {
            acc[tm][tn] = __builtin_amdgcn_mfma_f32_16x16x32_bf16(ah[tm], bl[tn], acc[tm][tn], 0, 0, 0);
            acc[tm][tn] = __builtin_amdgcn_mfma_f32_16x16x32_bf16(al[tm], bh[tn], acc[tm][tn], 0, 0, 0);
          }
        }
    }
  }

  const int quad = lane >> 4, cl = lane & 15;
#pragma unroll
  for (int tm = 0; tm < 2; ++tm) {
#pragma unroll
    for (int r = 0; r < 4; ++r) {
      const int row = m0 + waveM * 32 + tm * 16 + quad * 4 + r;
#pragma unroll
      for (int tn = 0; tn < 2; ++tn) {
        const int col = n0 + waveN * 32 + tn * 16 + cl;
        float v = acc[tm][tn][r];
        if (o.bias) v += o.bias[col];
        if (o.add) v += o.add[(size_t)row * 512 + col];
        if (o.act) v = tanh_fast(v);
        if (o.outf) o.outf[(size_t)row * 512 + col] = v;
        if (o.outh) {
          __bf16 h = (__bf16)v;
          o.outh[(size_t)row * 512 + col] = h;
          o.outl[(size_t)row * 512 + col] = (__bf16)(v - (float)h);
        }
      }
    }
  }
}

// ------------- fused chain kernel v2 -----------------------------------------
// 512 threads (8 waves), 128 KB LDS: P[64x512] bf16 swizzled + B double-buffer
// 2 x [512n x 32k].  Wave w owns output M64 x N64 (n-base w*64): acc 2x2
// f32x16.  Per k32-step: 4 A-frags + 4 B-frags (ds_read_b128) + 8 MFMA.
// P swizzle: byte ^= (row&7)<<4 within 1024B rows -> conflict-free A reads.
// B tile rows are 64B: swizzle kb ^= ((n>>1)&3)<<4 -> 8 consecutive rows hit
// 8 distinct 128B-window slots -> conflict-free B reads.  gl_lds16 writes
// LDS linearly, so the swizzle is applied on the per-lane GLOBAL source
// address (g' = g ^ ((rl>>1)&3), a per-lane constant).
DEV int p_byte(int row, int colb) { return row * 1024 + (colb ^ ((row & 7) << 4)); }
DEV int b_byte(int n, int kb)    { return n * 64  + (kb  ^ (((n >> 1) & 3) << 4)); }

__global__ __launch_bounds__(512, 2) void chain_kernel(
    const float* __restrict__ A, const float* __restrict__ C,
    const __bf16* __restrict__ Wgc, const __bf16* __restrict__ Wes,
    const float* __restrict__ p1, const float* __restrict__ q1,
    const float* __restrict__ p2, const float* __restrict__ q2,
    const float* __restrict__ b_esa, float* __restrict__ S) {
  __shared__ __bf16 P[64 * 512];        // 64 KB
  __shared__ __bf16 Bt[2][512 * 32];    // 2 x 32 KB
  const int t = threadIdx.x, lane = t & 63, w = t >> 6;
  const int blk = blockIdx.x;           // 512 blocks
  const size_t r0 = (size_t)blk * 64;   // global row = (b*128+i)*128 + j
  const int bi = blk >> 1;              // b*128 + i
  const int b = bi >> 7;
  const int j0 = (blk & 1) * 64;

  // staging lane constants: band of 16 rows per inst; lane -> (rl, g)
  const int rl = lane >> 2;                 // row within band (0..15)
  const int gp = (lane & 3) ^ ((rl >> 1) & 3);  // pre-swizzled 16B granule
  const size_t g_lane_off = (size_t)rl * 1024 + (size_t)gp * 16;  // bytes

  // issue one 32KB B-tile stage for k-step s into buf (4 gl_lds16 per wave)
  auto stage_issue = [&](const __bf16* W, int s, __bf16* buf) {
    const char* gbase = (const char*)W + (size_t)(w * 64) * 1024 + (size_t)s * 64 + g_lane_off;
    char* lbase = (char*)buf + (size_t)(w * 64) * 64;
#pragma unroll
    for (int i = 0; i < 4; ++i)
      gl_lds16(gbase + (size_t)i * 16 * 1024, lbase + i * 16 * 64);
  };

  // ---- prologue: issue stage-0 B-tile, then fill P = tanh(A[i] + C[j]) ----
  stage_issue(Wgc, 0, Bt[0]);
  {
    const float* arow = A + (size_t)bi * 512;
    const float* cbase = C + ((size_t)(b * 128 + j0)) * 512;
#pragma unroll
    for (int c = 0; c < 8; ++c) {
      int chunk = c * 512 + t;            // 4096 chunks = 64 rows x 64 x 8 floats
      int row = chunk >> 6;
      int colf = (chunk & 63) * 8;
      const float* ap = arow + colf;
      const float* cp = cbase + (size_t)row * 512 + colf;
      float av[8], cv[8];
      *(float4*)&av[0] = *(const float4*)ap;
      *(float4*)&av[4] = *(const float4*)(ap + 4);
      *(float4*)&cv[0] = *(const float4*)cp;
      *(float4*)&cv[4] = *(const float4*)(cp + 4);
      bf16x8 o;
#pragma unroll
      for (int e = 0; e < 8; ++e) o[e] = (__bf16)tanh_fast(av[e] + cv[e]);
      *(bf16x8*)((char*)P + p_byte(row, colf * 2)) = o;
    }
  }
  __syncthreads();

  const int ml = lane & 31, kl = lane >> 5;
  const int cl = lane & 31, lg = lane >> 5;

  f32x16 acc[2][2];
#pragma unroll
  for (int tm = 0; tm < 2; ++tm)
#pragma unroll
    for (int tn = 0; tn < 2; ++tn) acc[tm][tn] = (f32x16)0.f;

  const __bf16* Wst[3] = {Wgc, Wgc, Wes};

#pragma unroll 1
  for (int st = 0; st < 3; ++st) {
    const __bf16* W = Wst[st];
#pragma unroll 1
    for (int s = 0; s < 16; ++s) {
      // prefetch next tile (or next stage's step-0 tile) into the other buffer
      if (s < 15) stage_issue(W, s + 1, Bt[(s + 1) & 1]);
      else if (st < 2) stage_issue(Wst[st + 1], 0, Bt[0]);

      const char* bp = (const char*)Bt[s & 1];
      bf16x8 af[2][2], bfr[2][2];
#pragma unroll
      for (int tm = 0; tm < 2; ++tm)
#pragma unroll
        for (int mk = 0; mk < 2; ++mk)
          af[tm][mk] = *(const bf16x8*)((const char*)P +
              p_byte(tm * 32 + ml, s * 64 + mk * 32 + kl * 16));
#pragma unroll
      for (int tn = 0; tn < 2; ++tn)
#pragma unroll
        for (int mk = 0; mk < 2; ++mk)
          bfr[tn][mk] = *(const bf16x8*)(bp +
              b_byte(w * 64 + tn * 32 + ml, mk * 32 + kl * 16));
#pragma unroll
      for (int mk = 0; mk < 2; ++mk)
#pragma unroll
        for (int tm = 0; tm < 2; ++tm)
#pragma unroll
          for (int tn = 0; tn < 2; ++tn)
            acc[tm][tn] = __builtin_amdgcn_mfma_f32_32x32x16_bf16(
                af[tm][mk], bfr[tn][mk], acc[tm][tn], 0, 0, 0);

      __syncthreads();  // drains vmcnt (staged tile ready) + lgkm; syncs buffers
    }

    if (st < 2) {
      // epilogue: P = tanh(acc + p[i] + q[j]), reset acc
      const float* pv = (st == 0 ? p1 : p2) + (size_t)bi * 512;
      const float* qv = (st == 0 ? q1 : q2) + ((size_t)(b * 128 + j0)) * 512;
#pragma unroll
      for (int tn = 0; tn < 2; ++tn) {
        const int col = w * 64 + tn * 32 + cl;
        const float pcol = pv[col];
#pragma unroll
        for (int tm = 0; tm < 2; ++tm) {
#pragma unroll
          for (int reg = 0; reg < 16; ++reg) {
            const int row = tm * 32 + (reg & 3) + 8 * (reg >> 2) + 4 * lg;
            float v = acc[tm][tn][reg] + pcol + qv[(size_t)row * 512 + col];
            *(__bf16*)((char*)P + p_byte(row, col * 2)) = (__bf16)tanh_fast(v);
          }
          acc[tm][tn] = (f32x16)0.f;
        }
      }
      __syncthreads();  // P writes visible before next stage reads
    } else {
      // final epilogue: S = acc + b_esa
#pragma unroll
      for (int tn = 0; tn < 2; ++tn) {
        const int col = w * 64 + tn * 32 + cl;
        const float bcol = b_esa[col];
#pragma unroll
        for (int tm = 0; tm < 2; ++tm)
#pragma unroll
          for (int reg = 0; reg < 16; ++reg) {
            const int row = tm * 32 + (reg & 3) + 8 * (reg >> 2) + 4 * lg;
            S[(r0 + row) * 512 + col] = acc[tm][tn][reg] + bcol;
          }
      }
    }
  }
}

// ------------- softmax over axis i (no max pass: |s| bounded), then sum over j --
__global__ __launch_bounds__(256) void softmax_l_kernel(
    const float* __restrict__ S, float* __restrict__ Lb) {
  int idx = blockIdx.x * 256 + threadIdx.x;   // = (b*128 + j)*512 + d
  int d = idx & 511;
  int j = (idx >> 9) & 127;
  int b = idx >> 16;
  const float* p = S + ((size_t)b * 16384 + j) * 512 + d;  // i = 0
  float l = 0.f;
#pragma unroll 8
  for (int ii = 0; ii < 128; ++ii) l += __expf(p[(size_t)ii * 65536]);
  Lb[idx] = __frcp_rn(l);
}

__global__ __launch_bounds__(256) void softmax_out_kernel(
    const float* __restrict__ S, const float* __restrict__ Lb,
    float* __restrict__ outp) {
  int idx = blockIdx.x * 256 + threadIdx.x;   // = (b*128 + i)*512 + d
  int d = idx & 511;
  int i = (idx >> 9) & 127;
  int b = idx >> 16;
  const float* sp = S + ((size_t)(b * 128 + i)) * 65536 + d;  // j = 0
  const float* lp = Lb + (size_t)b * 65536 + d;
  float acc = 0.f;
#pragma unroll 8
  for (int jj = 0; jj < 128; ++jj) {
    float s = sp[(size_t)jj * 512];
    acc += __expf(s) * lp[(size_t)jj * 512] * s;
  }
  outp[idx] = acc;
}

// --------------------------------------------------------------------------------
extern "C" void kernel_launch(void* const* d_in, const int* in_sizes, int n_in,
                              void* d_out, int out_size, void* d_ws, size_t ws_size,
                              hipStream_t stream) {
  const float* x0    = (const float*)d_in[0];
  const float* W_rel = (const float*)d_in[1];
  const float* b_rel = (const float*)d_in[2];
  const float* W_go  = (const float*)d_in[3];
  const float* b_go  = (const float*)d_in[4];
  const float* W_gr  = (const float*)d_in[5];
  const float* b_gr  = (const float*)d_in[6];
  const float* W_esa = (const float*)d_in[7];
  const float* b_esa = (const float*)d_in[8];

  const float* Wrel_top = W_rel;
  const float* Wrel_bot = W_rel + 512 * 512;
  const float* Wgr_a = W_gr;
  const float* Wgr_b = W_gr + 512 * 512;
  const float* Wgr_c = W_gr + 2 * 512 * 512;

  char* ws = (char*)d_ws;
  size_t off = 0;
  auto alloc = [&](size_t bytes) -> void* {
    void* p = ws + off;
    off += (bytes + 255) & ~(size_t)255;
    return p;
  };
  const size_t NREL = 16777216ull;  // B*N*N*D
  float*  S  = (float*)alloc(NREL * 4);        // 64 MB
  float* p0t  = (float*)alloc(131072 * 4);
  float* q0t  = (float*)alloc(131072 * 4);
  float* Abuf = (float*)alloc(131072 * 4);
  float* Cbuf = (float*)alloc(131072 * 4);
  float* p1   = (float*)alloc(131072 * 4);
  float* q1   = (float*)alloc(131072 * 4);
  float* p2   = (float*)alloc(131072 * 4);
  float* q2   = (float*)alloc(131072 * 4);
  float* dvec = (float*)alloc(512 * 4);
  float* Lb   = (float*)alloc(131072 * 4);
  __bf16* x0h = (__bf16*)alloc(131072 * 2);
  __bf16* x0l = (__bf16*)alloc(131072 * 2);
  __bf16* x1h = (__bf16*)alloc(131072 * 2);
  __bf16* x1l = (__bf16*)alloc(131072 * 2);
  __bf16* x2h = (__bf16*)alloc(131072 * 2);
  __bf16* x2l = (__bf16*)alloc(131072 * 2);
  __bf16* u0h = (__bf16*)alloc(131072 * 2);
  __bf16* u0l = (__bf16*)alloc(131072 * 2);
  __bf16* v0h = (__bf16*)alloc(131072 * 2);
  __bf16* v0l = (__bf16*)alloc(131072 * 2);
  __bf16* Wgo_h = (__bf16*)alloc(262144 * 2);
  __bf16* Wgo_l = (__bf16*)alloc(262144 * 2);
  __bf16* Wrt_h = (__bf16*)alloc(262144 * 2);
  __bf16* Wrt_l = (__bf16*)alloc(262144 * 2);
  __bf16* Wrb_h = (__bf16*)alloc(262144 * 2);
  __bf16* Wrb_l = (__bf16*)alloc(262144 * 2);
  __bf16* Wga_h = (__bf16*)alloc(262144 * 2);
  __bf16* Wga_l = (__bf16*)alloc(262144 * 2);
  __bf16* Wgb_h = (__bf16*)alloc(262144 * 2);
  __bf16* Wgb_l = (__bf16*)alloc(262144 * 2);
  __bf16* Wgc_h = (__bf16*)alloc(262144 * 2);
  __bf16* Wgc_l = (__bf16*)alloc(262144 * 2);
  __bf16* Wes_h = (__bf16*)alloc(262144 * 2);
  __bf16* Wes_l = (__bf16*)alloc(262144 * 2);

  float* x3out  = (float*)d_out;             // output 0
  float* relout = (float*)d_out + 131072;    // output 1

  Prep pp;
  pp.w[0] = {W_go, Wgo_h, Wgo_l};
  pp.w[1] = {Wrel_top, Wrt_h, Wrt_l};
  pp.w[2] = {Wrel_bot, Wrb_h, Wrb_l};
  pp.w[3] = {Wgr_a, Wga_h, Wga_l};
  pp.w[4] = {Wgr_b, Wgb_h, Wgb_l};
  pp.w[5] = {Wgr_c, Wgc_h, Wgc_l};
  pp.w[6] = {W_esa, Wes_h, Wes_l};
  pp.x0 = x0; pp.x0h = x0h; pp.x0l = x0l;
  pp.b_rel = b_rel; pp.Wgrc = Wgr_c; pp.b_gr = b_gr; pp.dvec = dvec;
  prep_kernel<<<dim3(256, 9), 256, 0, stream>>>(pp);

  MBatch m1 = {};
  m1.op[0] = {x0h, x0l, Wgo_h, Wgo_l, b_go, nullptr, nullptr, x1h, x1l, 1};
  m1.op[1] = {x0h, x0l, Wrt_h, Wrt_l, nullptr, nullptr, nullptr, u0h, u0l, 0};
  m1.op[2] = {x0h, x0l, Wrb_h, Wrb_l, nullptr, nullptr, nullptr, v0h, v0l, 0};
  m1.op[3] = {x0h, x0l, Wga_h, Wga_l, nullptr, nullptr, p0t, nullptr, nullptr, 0};
  m1.op[4] = {x0h, x0l, Wgb_h, Wgb_l, nullptr, nullptr, q0t, nullptr, nullptr, 0};
  mfma_small_kernel<<<dim3(32, 5), 256, 0, stream>>>(m1);

  MBatch m2 = {};
  m2.op[0] = {x1h, x1l, Wgo_h, Wgo_l, b_go, nullptr, nullptr, x2h, x2l, 1};
  m2.op[1] = {u0h, u0l, Wgc_h, Wgc_l, dvec, p0t, Abuf, nullptr, nullptr, 0};
  m2.op[2] = {v0h, v0l, Wgc_h, Wgc_l, nullptr, q0t, Cbuf, nullptr, nullptr, 0};
  m2.op[3] = {x1h, x1l, Wga_h, Wga_l, b_gr, nullptr, p1, nullptr, nullptr, 0};
  m2.op[4] = {x1h, x1l, Wgb_h, Wgb_l, nullptr, nullptr, q1, nullptr, nullptr, 0};
  mfma_small_kernel<<<dim3(32, 5), 256, 0, stream>>>(m2);

  MBatch m3 = {};
  m3.op[0] = {x2h, x2l, Wgo_h, Wgo_l, b_go, nullptr, x3out, nullptr, nullptr, 1};
  m3.op[1] = {x2h, x2l, Wga_h, Wga_l, b_gr, nullptr, p2, nullptr, nullptr, 0};
  m3.op[2] = {x2h, x2l, Wgb_h, Wgb_l, nullptr, nullptr, q2, nullptr, nullptr, 0};
  mfma_small_kernel<<<dim3(32, 3), 256, 0, stream>>>(m3);

  // fused: rel1 (in LDS) -> rel2 -> rel3 -> S, one dispatch, B LDS-staged
  chain_kernel<<<512, 512, 0, stream>>>(Abuf, Cbuf, Wgc_h, Wes_h,
                                        p1, q1, p2, q2, b_esa, S);

  softmax_l_kernel<<<512, 256, 0, stream>>>(S, Lb);
  softmax_out_kernel<<<512, 256, 0, stream>>>(S, Lb, relout);
}